// Round 12
// baseline (508.616 us; speedup 1.0000x reference)
//
#include <hip/hip_runtime.h>
#include <hip/hip_fp16.h>
#include <math.h>

// Problem constants (match reference)
#define NN   100000
#define EE   3200000
#define GG   512
#define INC  128
#define D1   64        // H1*C1 = 8*8
#define OUTC 64
#define HID  128
#define NEG  0.2f

// Two-level CSR binning (128-node bins)
#define BINS2 782      // ceil(NN/128)
#define BCAP2 4864     // Poisson(4092) + 12 sigma; overflow-guarded

typedef __attribute__((ext_vector_type(2))) float v2f;
typedef __attribute__((ext_vector_type(4))) float v4f;   // native vec for nt-store

// ===========================================================================
// P2: bucket scatter. Block = 2048 edges. LDS histogram over 782 coarse bins
// (bin = dst>>7), ONE global atomic per (block,bin), then scatter packed
// (src<<7)|(dst&127) into the bin's segment.
// ===========================================================================
__global__ __launch_bounds__(256)
void k_bucket(const int* __restrict__ srcv, const int* __restrict__ dstv,
              int* __restrict__ cursor, int* __restrict__ bucket) {
    __shared__ int hcnt[BINS2];
    __shared__ int hbase[BINS2];
    int tid = threadIdx.x;
    for (int i = tid; i < BINS2; i += 256) hcnt[i] = 0;
    __syncthreads();
    int e0 = blockIdx.x * 2048;
    int bn[8], rk[8], pk[8];
#pragma unroll
    for (int q = 0; q < 8; ++q) {
        int e = e0 + q * 256 + tid;
        if (e < EE) {
            int s = srcv[e], d = dstv[e];
            bn[q] = d >> 7;
            pk[q] = (s << 7) | (d & 127);
            rk[q] = atomicAdd(&hcnt[bn[q]], 1);   // LDS atomic
        } else bn[q] = -1;
    }
    __syncthreads();
    for (int i = tid; i < BINS2; i += 256) {
        int c = hcnt[i];
        hbase[i] = c ? atomicAdd(&cursor[i], c) : 0;
    }
    __syncthreads();
#pragma unroll
    for (int q = 0; q < 8; ++q) {
        if (bn[q] >= 0) {
            int p = hbase[bn[q]] + rk[q];
            if (p < BCAP2) bucket[bn[q] * BCAP2 + p] = pk[q];
        }
    }
}

// ===========================================================================
// P3: per-bin fine CSR. One block per 128-node bin. Two streaming passes
// over the bin segment (sits in L2): LDS hist+scan -> rbeg/rend; scatter col.
// ===========================================================================
__global__ __launch_bounds__(256)
void k_binCSR(const int* __restrict__ cursor, const int* __restrict__ bucket,
              int* __restrict__ col, int* __restrict__ rbeg, int* __restrict__ rend) {
    __shared__ int cnt[128];
    __shared__ int tmp[256];
    __shared__ int cur[128];
    int b = blockIdx.x, tid = threadIdx.x;
    if (tid < 128) cnt[tid] = 0;
    __syncthreads();
    int m = cursor[b]; if (m > BCAP2) m = BCAP2;
    const int* seg = bucket + b * BCAP2;
    for (int i = tid; i < m; i += 256)
        atomicAdd(&cnt[seg[i] & 127], 1);
    __syncthreads();
    int v = (tid < 128) ? cnt[tid] : 0;
    tmp[tid] = v;
    __syncthreads();
    for (int off = 1; off < 256; off <<= 1) {
        int t = (tid >= off) ? tmp[tid - off] : 0;
        __syncthreads();
        tmp[tid] += t;
        __syncthreads();
    }
    if (tid < 128) {
        int excl = tmp[tid] - v;
        int n = b * 128 + tid;
        if (n < NN) {
            rbeg[n] = b * BCAP2 + excl;
            rend[n] = b * BCAP2 + excl + v;
        }
        cur[tid] = excl;
    }
    __syncthreads();
    for (int i = tid; i < m; i += 256) {
        int pkv = seg[i];
        int r = atomicAdd(&cur[pkv & 127], 1);
        col[b * BCAP2 + r] = pkv >> 7;
    }
}

// ===========================================================================
// K1: h1 = x @ W1, stored fp8 e4m3 in TWO half-sliced tables (heads 0-3 /
// 4-7, 3.2 MB each -> per-XCD-L2-resident in the agg). a_s1 fp16, sliced.
// ===========================================================================
__global__ __launch_bounds__(256)
void k_lin1(const float* __restrict__ x, const float* __restrict__ W1,
            const float* __restrict__ att_s, const float* __restrict__ att_d,
            unsigned int* __restrict__ Ha, unsigned int* __restrict__ Hb,
            __half* __restrict__ aSa, __half* __restrict__ aSb,
            float* __restrict__ a_d) {
    __shared__ float4 sW4[INC * 16];     // 32 KB
    __shared__ float sx[16][INC + 4];
    __shared__ float sh[16][D1];
    __shared__ float satt[2 * D1];
    int tid = threadIdx.x;
    const float4* W4 = (const float4*)W1;
    for (int i = tid; i < INC * 16; i += 256) sW4[i] = W4[i];
    if (tid < 128) satt[tid] = (tid < 64) ? att_s[tid] : att_d[tid - 64];
    int node0 = blockIdx.x * 16;
    for (int i = tid; i < 16 * 32; i += 256) {
        int r = i >> 5, kk = i & 31;
        float4 v = ((const float4*)x)[(node0 + r) * 32 + kk];
        sx[r][kk * 4 + 0] = v.x; sx[r][kk * 4 + 1] = v.y;
        sx[r][kk * 4 + 2] = v.z; sx[r][kk * 4 + 3] = v.w;
    }
    __syncthreads();
    int r = tid >> 4, cg = tid & 15;
    float4 acc = {0.f, 0.f, 0.f, 0.f};
#pragma unroll 8
    for (int k = 0; k < INC; ++k) {
        float xv = sx[r][k];
        float4 wv = sW4[k * 16 + cg];
        acc.x = fmaf(xv, wv.x, acc.x);
        acc.y = fmaf(xv, wv.y, acc.y);
        acc.z = fmaf(xv, wv.z, acc.z);
        acc.w = fmaf(xv, wv.w, acc.w);
    }
    int p = __builtin_amdgcn_cvt_pk_fp8_f32(acc.x, acc.y, 0, false);
    p = __builtin_amdgcn_cvt_pk_fp8_f32(acc.z, acc.w, p, true);
    unsigned int* Ht = (cg < 8) ? Ha : Hb;
    Ht[(node0 + r) * 8 + (cg & 7)] = (unsigned int)p;
    sh[r][cg * 4 + 0] = acc.x; sh[r][cg * 4 + 1] = acc.y;
    sh[r][cg * 4 + 2] = acc.z; sh[r][cg * 4 + 3] = acc.w;
    __syncthreads();
    if (tid < 128) {                 // 16 nodes x 8 heads
        int rr = tid >> 3, hh = tid & 7;
        float as = 0.f, ad = 0.f;
#pragma unroll
        for (int j = 0; j < 8; ++j) {
            float v = sh[rr][hh * 8 + j];
            as = fmaf(v, satt[hh * 8 + j], as);
            ad = fmaf(v, satt[64 + hh * 8 + j], ad);
        }
        int nb = node0 + rr;
        __half* aSt = (hh < 4) ? aSa : aSb;
        aSt[nb * 4 + (hh & 3)] = __float2half(as);
        a_d[nb * 8 + hh] = ad;
    }
}

// ===========================================================================
// Agg layer 1, head-half-sliced. Block -> (node-group, half) via blockIdx%8:
// bid%8<4 -> half 0 (XCDs 0-3 under round-robin dispatch), else half 1 ->
// each XCD's random working set = 3.2 MB table + 0.8 MB a_s slice (fits L2).
// Wave = 2 nodes x 8 slots x 4 lanes (lane = head-in-half, uint2 fp8).
// nt col loads / nt out stores keep streams out of L2.
// ===========================================================================
__global__ __launch_bounds__(256, 8)
void k_gat_agg1(const int* __restrict__ rbeg, const int* __restrict__ rend,
                const int* __restrict__ col,
                const __half* __restrict__ aSa, const __half* __restrict__ aSb,
                const float* __restrict__ a_d,
                const unsigned int* __restrict__ Ha, const unsigned int* __restrict__ Hb,
                const float* __restrict__ b1, float* __restrict__ out) {
    int bid = blockIdx.x;
    int ng   = (bid >> 3) * 4 + (bid & 3);
    int half = (bid >> 2) & 1;
    int wv = threadIdx.x >> 6;
    int lane = threadIdx.x & 63;
    int hn = lane >> 5;
    int d = ng * 8 + wv * 2 + hn;
    int gs = (lane >> 2) & 7;   // slot 0..7
    int l = lane & 3;           // head within half
    int hd = half * 4 + l;      // true head
    const uint2* hp = (const uint2*)(half ? Hb : Ha);
    const __half* asp = half ? aSb : aSa;
    int rb = rbeg[d], re = rend[d];
    float adh = a_d[d * 8 + hd];
    uint2 rself = hp[d * 4 + l];
    float asself = __half2float(asp[d * 4 + l]);
    float ac[8] = {0.f,0.f,0.f,0.f,0.f,0.f,0.f,0.f};
    float denom = 0.f;
    int e = rb + gs;
    int s[4];
#pragma unroll
    for (int q = 0; q < 4; ++q) s[q] = __builtin_nontemporal_load(col + e + 8 * q);
    for (; e + 24 < re; ) {
        uint2 rr[4]; float asv[4]; int sn[4];
#pragma unroll
        for (int q = 0; q < 4; ++q) rr[q] = hp[s[q] * 4 + l];
#pragma unroll
        for (int q = 0; q < 4; ++q) asv[q] = __half2float(asp[s[q] * 4 + l]);
        int en = e + 32;
#pragma unroll
        for (int q = 0; q < 4; ++q) sn[q] = __builtin_nontemporal_load(col + en + 8 * q);
#pragma unroll
        for (int q = 0; q < 4; ++q) {
            float xx = asv[q] + adh;
            xx = xx >= 0.f ? xx : NEG * xx;
            float w = __expf(xx);
            denom += w;
            v2f f0 = __builtin_amdgcn_cvt_pk_f32_fp8((int)rr[q].x, false);
            v2f f1 = __builtin_amdgcn_cvt_pk_f32_fp8((int)rr[q].x, true);
            v2f f2 = __builtin_amdgcn_cvt_pk_f32_fp8((int)rr[q].y, false);
            v2f f3 = __builtin_amdgcn_cvt_pk_f32_fp8((int)rr[q].y, true);
            ac[0] = fmaf(f0.x, w, ac[0]); ac[1] = fmaf(f0.y, w, ac[1]);
            ac[2] = fmaf(f1.x, w, ac[2]); ac[3] = fmaf(f1.y, w, ac[3]);
            ac[4] = fmaf(f2.x, w, ac[4]); ac[5] = fmaf(f2.y, w, ac[5]);
            ac[6] = fmaf(f3.x, w, ac[6]); ac[7] = fmaf(f3.y, w, ac[7]);
        }
        e = en;
#pragma unroll
        for (int q = 0; q < 4; ++q) s[q] = sn[q];
    }
    for (; e < re; e += 8) {
        int s0 = __builtin_nontemporal_load(col + e);
        uint2 r0 = hp[s0 * 4 + l];
        float x0 = __half2float(asp[s0 * 4 + l]) + adh;
        x0 = x0 >= 0.f ? x0 : NEG * x0;
        float w0 = __expf(x0);
        denom += w0;
        v2f f0 = __builtin_amdgcn_cvt_pk_f32_fp8((int)r0.x, false);
        v2f f1 = __builtin_amdgcn_cvt_pk_f32_fp8((int)r0.x, true);
        v2f f2 = __builtin_amdgcn_cvt_pk_f32_fp8((int)r0.y, false);
        v2f f3 = __builtin_amdgcn_cvt_pk_f32_fp8((int)r0.y, true);
        ac[0] = fmaf(f0.x, w0, ac[0]); ac[1] = fmaf(f0.y, w0, ac[1]);
        ac[2] = fmaf(f1.x, w0, ac[2]); ac[3] = fmaf(f1.y, w0, ac[3]);
        ac[4] = fmaf(f2.x, w0, ac[4]); ac[5] = fmaf(f2.y, w0, ac[5]);
        ac[6] = fmaf(f3.x, w0, ac[6]); ac[7] = fmaf(f3.y, w0, ac[7]);
    }
    if (gs == 0) {      // self-loop contribution
        float es = asself + adh;
        es = es >= 0.f ? es : NEG * es;
        float w = __expf(es);
        denom += w;
        v2f f0 = __builtin_amdgcn_cvt_pk_f32_fp8((int)rself.x, false);
        v2f f1 = __builtin_amdgcn_cvt_pk_f32_fp8((int)rself.x, true);
        v2f f2 = __builtin_amdgcn_cvt_pk_f32_fp8((int)rself.y, false);
        v2f f3 = __builtin_amdgcn_cvt_pk_f32_fp8((int)rself.y, true);
        ac[0] = fmaf(f0.x, w, ac[0]); ac[1] = fmaf(f0.y, w, ac[1]);
        ac[2] = fmaf(f1.x, w, ac[2]); ac[3] = fmaf(f1.y, w, ac[3]);
        ac[4] = fmaf(f2.x, w, ac[4]); ac[5] = fmaf(f2.y, w, ac[5]);
        ac[6] = fmaf(f3.x, w, ac[6]); ac[7] = fmaf(f3.y, w, ac[7]);
    }
#pragma unroll
    for (int i = 0; i < 8; ++i) {     // reduce 8 slots (gs = lane bits 2..4)
        ac[i] += __shfl_xor(ac[i], 4, 64);
        ac[i] += __shfl_xor(ac[i], 8, 64);
        ac[i] += __shfl_xor(ac[i], 16, 64);
    }
    denom += __shfl_xor(denom, 4, 64);
    denom += __shfl_xor(denom, 8, 64);
    denom += __shfl_xor(denom, 16, 64);
    if (gs == 0) {
        float inv = 1.0f / denom;
        float4 b0 = ((const float4*)b1)[hd * 2];
        float4 b4 = ((const float4*)b1)[hd * 2 + 1];
        v4f r0, r1;
        r0.x = fmaf(ac[0], inv, b0.x); r0.x = r0.x > 0.f ? r0.x : expm1f(r0.x);
        r0.y = fmaf(ac[1], inv, b0.y); r0.y = r0.y > 0.f ? r0.y : expm1f(r0.y);
        r0.z = fmaf(ac[2], inv, b0.z); r0.z = r0.z > 0.f ? r0.z : expm1f(r0.z);
        r0.w = fmaf(ac[3], inv, b0.w); r0.w = r0.w > 0.f ? r0.w : expm1f(r0.w);
        r1.x = fmaf(ac[4], inv, b4.x); r1.x = r1.x > 0.f ? r1.x : expm1f(r1.x);
        r1.y = fmaf(ac[5], inv, b4.y); r1.y = r1.y > 0.f ? r1.y : expm1f(r1.y);
        r1.z = fmaf(ac[6], inv, b4.z); r1.z = r1.z > 0.f ? r1.z : expm1f(r1.z);
        r1.w = fmaf(ac[7], inv, b4.w); r1.w = r1.w > 0.f ? r1.w : expm1f(r1.w);
        __builtin_nontemporal_store(r0, (v4f*)out + d * 16 + hd * 2);
        __builtin_nontemporal_store(r1, (v4f*)out + d * 16 + hd * 2 + 1);
    }
}

// ===========================================================================
// K5: h2 = hin @ W2, stored fp8 into TWO ch-half slices; a_s2/a_d2 fp32.
// ===========================================================================
__global__ __launch_bounds__(256)
void k_lin2(const float* __restrict__ hin, const float* __restrict__ W2,
            const float* __restrict__ att_s, const float* __restrict__ att_d,
            unsigned int* __restrict__ Ha, unsigned int* __restrict__ Hb,
            float* __restrict__ a_s, float* __restrict__ a_d) {
    __shared__ float4 sW4[D1 * 16];      // 16 KB
    __shared__ float sx[16][D1 + 4];
    __shared__ float satt[2 * OUTC];
    int tid = threadIdx.x;
    const float4* W4 = (const float4*)W2;
    for (int i = tid; i < D1 * 16; i += 256) sW4[i] = W4[i];
    if (tid < 128) satt[tid] = (tid < 64) ? att_s[tid] : att_d[tid - 64];
    int node0 = blockIdx.x * 16;
    for (int i = tid; i < 16 * 16; i += 256) {
        int r = i >> 4, kk = i & 15;
        float4 v = ((const float4*)hin)[(node0 + r) * 16 + kk];
        sx[r][kk * 4 + 0] = v.x; sx[r][kk * 4 + 1] = v.y;
        sx[r][kk * 4 + 2] = v.z; sx[r][kk * 4 + 3] = v.w;
    }
    __syncthreads();
    int r = tid >> 4, cg = tid & 15;
    float4 acc = {0.f, 0.f, 0.f, 0.f};
#pragma unroll 8
    for (int k = 0; k < D1; ++k) {
        float xv = sx[r][k];
        float4 wv = sW4[k * 16 + cg];
        acc.x = fmaf(xv, wv.x, acc.x);
        acc.y = fmaf(xv, wv.y, acc.y);
        acc.z = fmaf(xv, wv.z, acc.z);
        acc.w = fmaf(xv, wv.w, acc.w);
    }
    int n = node0 + r;
    int p = __builtin_amdgcn_cvt_pk_fp8_f32(acc.x, acc.y, 0, false);
    p = __builtin_amdgcn_cvt_pk_fp8_f32(acc.z, acc.w, p, true);
    unsigned int* Ht = (cg < 8) ? Ha : Hb;
    Ht[n * 8 + (cg & 7)] = (unsigned int)p;
    float vs = acc.x * satt[cg * 4] + acc.y * satt[cg * 4 + 1]
             + acc.z * satt[cg * 4 + 2] + acc.w * satt[cg * 4 + 3];
    float vd = acc.x * satt[64 + cg * 4] + acc.y * satt[64 + cg * 4 + 1]
             + acc.z * satt[64 + cg * 4 + 2] + acc.w * satt[64 + cg * 4 + 3];
    for (int off = 1; off < 16; off <<= 1) {
        vs += __shfl_xor(vs, off, 64);
        vd += __shfl_xor(vd, off, 64);
    }
    if (cg == 0) { a_s[n] = vs; a_d[n] = vd; }
}

// ===========================================================================
// Agg layer 2 (1 head), ch-half-sliced, same %8 half mapping. Fused bias +
// mean-pool (LDS staged, each block handles its half's 32 channels).
// ===========================================================================
__global__ __launch_bounds__(256, 8)
void k_gat_agg2(const int* __restrict__ rbeg, const int* __restrict__ rend,
                const int* __restrict__ col,
                const float* __restrict__ a_s, const float* __restrict__ a_d,
                const unsigned int* __restrict__ Ha, const unsigned int* __restrict__ Hb,
                const float* __restrict__ b2, const int* __restrict__ batch,
                float* __restrict__ pool, float* __restrict__ cnt) {
    __shared__ float sv[8][32];
    __shared__ int sgi[8];
    int bid = blockIdx.x;
    int ng   = (bid >> 3) * 4 + (bid & 3);
    int half = (bid >> 2) & 1;
    int wv = threadIdx.x >> 6;
    int lane = threadIdx.x & 63;
    int hn = lane >> 5;
    int idx = wv * 2 + hn;
    int d = ng * 8 + idx;
    int gs = (lane >> 2) & 7;
    int l = lane & 3;             // ch-group within half (8 ch)
    const uint2* hp = (const uint2*)(half ? Hb : Ha);
    int rb = rbeg[d], re = rend[d];
    float ad = a_d[d];
    uint2 rself = hp[d * 4 + l];
    float asself = a_s[d];
    if (gs == 0 && l == 0) sgi[idx] = batch[d];
    float ac[8] = {0.f,0.f,0.f,0.f,0.f,0.f,0.f,0.f};
    float denom = 0.f;
    int e = rb + gs;
    int s[4];
#pragma unroll
    for (int q = 0; q < 4; ++q) s[q] = __builtin_nontemporal_load(col + e + 8 * q);
    for (; e + 24 < re; ) {
        uint2 rr[4]; float asv[4]; int sn[4];
#pragma unroll
        for (int q = 0; q < 4; ++q) rr[q] = hp[s[q] * 4 + l];
#pragma unroll
        for (int q = 0; q < 4; ++q) asv[q] = a_s[s[q]];
        int en = e + 32;
#pragma unroll
        for (int q = 0; q < 4; ++q) sn[q] = __builtin_nontemporal_load(col + en + 8 * q);
#pragma unroll
        for (int q = 0; q < 4; ++q) {
            float xx = asv[q] + ad;
            xx = xx >= 0.f ? xx : NEG * xx;
            float w = __expf(xx);
            denom += w;
            v2f f0 = __builtin_amdgcn_cvt_pk_f32_fp8((int)rr[q].x, false);
            v2f f1 = __builtin_amdgcn_cvt_pk_f32_fp8((int)rr[q].x, true);
            v2f f2 = __builtin_amdgcn_cvt_pk_f32_fp8((int)rr[q].y, false);
            v2f f3 = __builtin_amdgcn_cvt_pk_f32_fp8((int)rr[q].y, true);
            ac[0] = fmaf(f0.x, w, ac[0]); ac[1] = fmaf(f0.y, w, ac[1]);
            ac[2] = fmaf(f1.x, w, ac[2]); ac[3] = fmaf(f1.y, w, ac[3]);
            ac[4] = fmaf(f2.x, w, ac[4]); ac[5] = fmaf(f2.y, w, ac[5]);
            ac[6] = fmaf(f3.x, w, ac[6]); ac[7] = fmaf(f3.y, w, ac[7]);
        }
        e = en;
#pragma unroll
        for (int q = 0; q < 4; ++q) s[q] = sn[q];
    }
    for (; e < re; e += 8) {
        int s0 = __builtin_nontemporal_load(col + e);
        uint2 r0 = hp[s0 * 4 + l];
        float x0 = a_s[s0] + ad;
        x0 = x0 >= 0.f ? x0 : NEG * x0;
        float w0 = __expf(x0);
        denom += w0;
        v2f f0 = __builtin_amdgcn_cvt_pk_f32_fp8((int)r0.x, false);
        v2f f1 = __builtin_amdgcn_cvt_pk_f32_fp8((int)r0.x, true);
        v2f f2 = __builtin_amdgcn_cvt_pk_f32_fp8((int)r0.y, false);
        v2f f3 = __builtin_amdgcn_cvt_pk_f32_fp8((int)r0.y, true);
        ac[0] = fmaf(f0.x, w0, ac[0]); ac[1] = fmaf(f0.y, w0, ac[1]);
        ac[2] = fmaf(f1.x, w0, ac[2]); ac[3] = fmaf(f1.y, w0, ac[3]);
        ac[4] = fmaf(f2.x, w0, ac[4]); ac[5] = fmaf(f2.y, w0, ac[5]);
        ac[6] = fmaf(f3.x, w0, ac[6]); ac[7] = fmaf(f3.y, w0, ac[7]);
    }
    if (gs == 0) {
        float es = asself + ad;
        es = es >= 0.f ? es : NEG * es;
        float w = __expf(es);
        denom += w;
        v2f f0 = __builtin_amdgcn_cvt_pk_f32_fp8((int)rself.x, false);
        v2f f1 = __builtin_amdgcn_cvt_pk_f32_fp8((int)rself.x, true);
        v2f f2 = __builtin_amdgcn_cvt_pk_f32_fp8((int)rself.y, false);
        v2f f3 = __builtin_amdgcn_cvt_pk_f32_fp8((int)rself.y, true);
        ac[0] = fmaf(f0.x, w, ac[0]); ac[1] = fmaf(f0.y, w, ac[1]);
        ac[2] = fmaf(f1.x, w, ac[2]); ac[3] = fmaf(f1.y, w, ac[3]);
        ac[4] = fmaf(f2.x, w, ac[4]); ac[5] = fmaf(f2.y, w, ac[5]);
        ac[6] = fmaf(f3.x, w, ac[6]); ac[7] = fmaf(f3.y, w, ac[7]);
    }
#pragma unroll
    for (int i = 0; i < 8; ++i) {
        ac[i] += __shfl_xor(ac[i], 4, 64);
        ac[i] += __shfl_xor(ac[i], 8, 64);
        ac[i] += __shfl_xor(ac[i], 16, 64);
    }
    denom += __shfl_xor(denom, 4, 64);
    denom += __shfl_xor(denom, 8, 64);
    denom += __shfl_xor(denom, 16, 64);
    if (gs == 0) {
        float inv = 1.0f / denom;
#pragma unroll
        for (int i = 0; i < 8; ++i)
            sv[idx][l * 8 + i] = fmaf(ac[i], inv, b2[half * 32 + l * 8 + i]);
    }
    __syncthreads();
    int tid = threadIdx.x;
    if (tid < 32) {
        float acc = sv[0][tid]; int curg = sgi[0];
        for (int r = 1; r < 8; ++r) {
            if (sgi[r] == curg) acc += sv[r][tid];
            else { atomicAdd(&pool[curg * 64 + half * 32 + tid], acc); curg = sgi[r]; acc = sv[r][tid]; }
        }
        atomicAdd(&pool[curg * 64 + half * 32 + tid], acc);
    } else if (tid == 32 && half == 0) {
        float c = 1.f; int curg = sgi[0];
        for (int r = 1; r < 8; ++r) {
            if (sgi[r] == curg) c += 1.f;
            else { atomicAdd(&cnt[curg], c); curg = sgi[r]; c = 1.f; }
        }
        atomicAdd(&cnt[curg], c);
    }
}

// K9: g = pool/cnt ; hidden = elu(g@lw1+lb1) ; out = hidden@lw2 + lb2
__global__ __launch_bounds__(128)
void k_mlp(const float* __restrict__ pool, const float* __restrict__ cnt,
           const float* __restrict__ lw1, const float* __restrict__ lb1,
           const float* __restrict__ lw2, const float* __restrict__ lb2,
           float* __restrict__ out) {
    __shared__ float sg[OUTC];
    __shared__ float sh[HID];
    int g = blockIdx.x, tid = threadIdx.x;
    float c = fmaxf(cnt[g], 1.0f);
    if (tid < OUTC) sg[tid] = pool[g * OUTC + tid] / c;
    __syncthreads();
    float acc = lb1[tid];
#pragma unroll 8
    for (int k = 0; k < OUTC; ++k)
        acc = fmaf(sg[k], lw1[k * HID + tid], acc);
    acc = acc > 0.f ? acc : expm1f(acc);
    sh[tid] = acc * lw2[tid];
    __syncthreads();
    for (int off = 64; off >= 1; off >>= 1) {
        if (tid < off) sh[tid] += sh[tid + off];
        __syncthreads();
    }
    if (tid == 0) out[g] = sh[0] + lb2[0];
}

extern "C" void kernel_launch(void* const* d_in, const int* in_sizes, int n_in,
                              void* d_out, int out_size, void* d_ws, size_t ws_size,
                              hipStream_t stream) {
    const float* x    = (const float*)d_in[0];
    const int*   ei   = (const int*)d_in[1];
    const int*   batch= (const int*)d_in[2];
    const float* W1   = (const float*)d_in[3];
    const float* as1  = (const float*)d_in[4];
    const float* ad1  = (const float*)d_in[5];
    const float* b1   = (const float*)d_in[6];
    const float* W2   = (const float*)d_in[7];
    const float* as2  = (const float*)d_in[8];
    const float* ad2  = (const float*)d_in[9];
    const float* b2   = (const float*)d_in[10];
    const float* lw1  = (const float*)d_in[11];
    const float* lb1  = (const float*)d_in[12];
    const float* lw2  = (const float*)d_in[13];
    const float* lb2  = (const float*)d_in[14];
    float* out = (float*)d_out;

    // workspace layout (~69 MB). H slices reused for layer 2 (H2a/H2b).
    unsigned int* Ha = (unsigned int*)d_ws;          // NN*8 uints (3.2 MB)
    unsigned int* Hb = Ha + (size_t)NN * 8;          // NN*8 uints (3.2 MB)
    float* B    = (float*)(Hb + (size_t)NN * 8);     // NN*64 fp32 (25.6 MB)
    float* aD1  = B + (size_t)NN * 64;               // N*8
    float* aS2  = aD1 + NN * 8;                      // N
    float* aD2  = aS2 + NN;                          // N
    float* pool = aD2 + NN;                          // G*64
    float* cnt  = pool + GG * 64;                    // G
    __half* aSa = (__half*)(cnt + GG);               // N*4 fp16 (0.8 MB)
    __half* aSb = aSa + (size_t)NN * 4;              // N*4 fp16
    int* rbeg   = (int*)(aSb + (size_t)NN * 4);      // N
    int* rend   = rbeg + NN;                         // N
    int* cursor = rend + NN;                         // BINS2
    int* bucket = cursor + BINS2;                    // BINS2*BCAP2 (15.2 MB)
    int* colv   = bucket + (size_t)BINS2 * BCAP2;    // BINS2*BCAP2 + 64 pad

    const int* srcv = ei;
    const int* dstv = ei + EE;

    hipMemsetAsync(cursor, 0, BINS2 * sizeof(int), stream);
    hipMemsetAsync(pool, 0, (size_t)(GG * 64 + GG) * sizeof(float), stream);

    // CSR build: two-level binning (128-node bins)
    k_bucket<<<(EE + 2047) / 2048, 256, 0, stream>>>(srcv, dstv, cursor, bucket);
    k_binCSR<<<BINS2, 256, 0, stream>>>(cursor, bucket, colv, rbeg, rend);

    // layer 1 (agg split into XCD-pinned head-halves)
    k_lin1    <<<NN / 16, 256, 0, stream>>>(x, W1, as1, ad1, Ha, Hb, aSa, aSb, aD1);
    k_gat_agg1<<<NN / 4, 256, 0, stream>>>(rbeg, rend, colv, aSa, aSb, aD1, Ha, Hb, b1, B);

    // layer 2 (agg split into XCD-pinned ch-halves; fused bias + mean-pool)
    k_lin2    <<<NN / 16, 256, 0, stream>>>(B, W2, as2, ad2, Ha, Hb, aS2, aD2);
    k_gat_agg2<<<NN / 4, 256, 0, stream>>>(rbeg, rend, colv, aS2, aD2, Ha, Hb, b2, batch, pool, cnt);

    // MLP head
    k_mlp<<<GG, 128, 0, stream>>>(pool, cnt, lw1, lb1, lw2, lb2, out);
}

// Round 13
// 386.373 us; speedup vs baseline: 1.3164x; 1.3164x over previous
//
#include <hip/hip_runtime.h>
#include <hip/hip_fp16.h>
#include <math.h>

// Problem constants (match reference)
#define NN   100000
#define EE   3200000
#define GG   512
#define INC  128
#define D1   64        // H1*C1 = 8*8
#define OUTC 64
#define HID  128
#define NEG  0.2f

// Two-level CSR binning
#define BINS 391       // ceil(NN/256)
#define BCAP 9216      // Poisson(8192) + 11 sigma; overflow-guarded
#define BKBLK 1563     // ceil(EE/2048) bucket blocks in the fused kernel

typedef __attribute__((ext_vector_type(2))) float v2f;

// ===========================================================================
// FUSED: [blocks 0..BKBLK) = bucket scatter  |  [BKBLK..) = lin1 GEMM.
// The two are data-independent; fusing lets the atomic-bound bucket work
// co-schedule with the VALU-bound GEMM instead of serializing on the stream.
// Shared LDS union via raw buffer (lin1's 45.8 KB is the max).
// ===========================================================================
__global__ __launch_bounds__(256)
void k_fused(const int* __restrict__ srcv, const int* __restrict__ dstv,
             int* __restrict__ cursor, int* __restrict__ bucket,
             const float* __restrict__ x, const float* __restrict__ W1,
             const float* __restrict__ att_s, const float* __restrict__ att_d,
             unsigned int* __restrict__ h1, __half* __restrict__ a_s,
             float* __restrict__ a_d) {
    __shared__ __align__(16) char smem[45824];
    int tid = threadIdx.x;
    if (blockIdx.x < BKBLK) {
        // ---------------- bucket scatter ----------------
        int* hcnt  = (int*)smem;          // BINS
        int* hbase = hcnt + BINS;         // BINS
        for (int i = tid; i < BINS; i += 256) hcnt[i] = 0;
        __syncthreads();
        int e0 = blockIdx.x * 2048;
        int bn[8], rk[8], pk[8];
#pragma unroll
        for (int q = 0; q < 8; ++q) {
            int e = e0 + q * 256 + tid;
            if (e < EE) {
                int s = srcv[e], d = dstv[e];
                bn[q] = d >> 8;
                pk[q] = (s << 8) | (d & 255);
                rk[q] = atomicAdd(&hcnt[bn[q]], 1);   // LDS atomic
            } else bn[q] = -1;
        }
        __syncthreads();
        for (int i = tid; i < BINS; i += 256) {
            int c = hcnt[i];
            hbase[i] = c ? atomicAdd(&cursor[i], c) : 0;
        }
        __syncthreads();
#pragma unroll
        for (int q = 0; q < 8; ++q) {
            if (bn[q] >= 0) {
                int p = hbase[bn[q]] + rk[q];
                if (p < BCAP) bucket[bn[q] * BCAP + p] = pk[q];
            }
        }
    } else {
        // ---------------- lin1: h1 = x @ W1 (fp8 store), attention dots ----
        float4* sW4 = (float4*)smem;                                   // 32768
        float (*sx)[INC + 4] = (float(*)[INC + 4])(smem + 32768);      // 8448
        float (*sh)[D1] = (float(*)[D1])(smem + 32768 + 8448);         // 4096
        float* satt = (float*)(smem + 32768 + 8448 + 4096);            // 512
        const float4* W4 = (const float4*)W1;
        for (int i = tid; i < INC * 16; i += 256) sW4[i] = W4[i];
        if (tid < 128) satt[tid] = (tid < 64) ? att_s[tid] : att_d[tid - 64];
        int node0 = (blockIdx.x - BKBLK) * 16;
        for (int i = tid; i < 16 * 32; i += 256) {
            int r = i >> 5, kk = i & 31;
            float4 v = ((const float4*)x)[(node0 + r) * 32 + kk];
            sx[r][kk * 4 + 0] = v.x; sx[r][kk * 4 + 1] = v.y;
            sx[r][kk * 4 + 2] = v.z; sx[r][kk * 4 + 3] = v.w;
        }
        __syncthreads();
        int r = tid >> 4, cg = tid & 15;
        float4 acc = {0.f, 0.f, 0.f, 0.f};
#pragma unroll 8
        for (int k = 0; k < INC; ++k) {
            float xv = sx[r][k];
            float4 wv = sW4[k * 16 + cg];
            acc.x = fmaf(xv, wv.x, acc.x);
            acc.y = fmaf(xv, wv.y, acc.y);
            acc.z = fmaf(xv, wv.z, acc.z);
            acc.w = fmaf(xv, wv.w, acc.w);
        }
        int p = __builtin_amdgcn_cvt_pk_fp8_f32(acc.x, acc.y, 0, false);
        p = __builtin_amdgcn_cvt_pk_fp8_f32(acc.z, acc.w, p, true);
        h1[(node0 + r) * 16 + cg] = (unsigned int)p;
        sh[r][cg * 4 + 0] = acc.x; sh[r][cg * 4 + 1] = acc.y;
        sh[r][cg * 4 + 2] = acc.z; sh[r][cg * 4 + 3] = acc.w;
        __syncthreads();
        if (tid < 128) {                 // 16 nodes x 8 heads
            int rr = tid >> 3, hh = tid & 7;
            float as = 0.f, ad = 0.f;
#pragma unroll
            for (int j = 0; j < 8; ++j) {
                float v = sh[rr][hh * 8 + j];
                as = fmaf(v, satt[hh * 8 + j], as);
                ad = fmaf(v, satt[64 + hh * 8 + j], ad);
            }
            int nb = node0 + rr;
            a_s[nb * 8 + hh] = __float2half(as);
            a_d[nb * 8 + hh] = ad;
        }
    }
}

// ===========================================================================
// P3: per-bin fine CSR. One block per bin (256 nodes). Two streaming passes
// over the bin segment (sits in L2): LDS hist+scan -> rbeg/rend; scatter col.
// ===========================================================================
__global__ __launch_bounds__(256)
void k_binCSR(const int* __restrict__ cursor, const int* __restrict__ bucket,
              int* __restrict__ col, int* __restrict__ rbeg, int* __restrict__ rend) {
    __shared__ int cnt[256];
    __shared__ int tmp[256];
    __shared__ int cur[256];
    int b = blockIdx.x, tid = threadIdx.x;
    cnt[tid] = 0;
    __syncthreads();
    int m = cursor[b]; if (m > BCAP) m = BCAP;
    const int* seg = bucket + b * BCAP;
    for (int i = tid; i < m; i += 256)
        atomicAdd(&cnt[seg[i] & 255], 1);
    __syncthreads();
    tmp[tid] = cnt[tid];
    __syncthreads();
    for (int off = 1; off < 256; off <<= 1) {
        int t = (tid >= off) ? tmp[tid - off] : 0;
        __syncthreads();
        tmp[tid] += t;
        __syncthreads();
    }
    int excl = tmp[tid] - cnt[tid];
    int n = b * 256 + tid;
    if (n < NN) {
        rbeg[n] = b * BCAP + excl;
        rend[n] = b * BCAP + excl + cnt[tid];
    }
    cur[tid] = excl;
    __syncthreads();
    for (int i = tid; i < m; i += 256) {
        int pkv = seg[i];
        int r = atomicAdd(&cur[pkv & 255], 1);
        col[b * BCAP + r] = pkv >> 8;
    }
}

// ===========================================================================
// Agg layer 1 (8 heads). Wave = 2 nodes x (4 edge-slots x 8 lanes), lane&7 =
// head = ch-group (uint2 fp8 row slice). Software-pipelined col prefetch.
// ===========================================================================
__global__ __launch_bounds__(256, 8)
void k_gat_agg1(const int* __restrict__ rbeg, const int* __restrict__ rend,
                const int* __restrict__ col,
                const __half* __restrict__ a_s, const float* __restrict__ a_d,
                const unsigned int* __restrict__ h1, const float* __restrict__ b1,
                float* __restrict__ out) {
    int wv = threadIdx.x >> 6;
    int lane = threadIdx.x & 63;
    int half = lane >> 5;
    int d = blockIdx.x * 8 + wv * 2 + half;
    int gs = (lane >> 3) & 3;   // slot within node
    int l = lane & 7;           // head / ch-group
    int rb = rbeg[d], re = rend[d];
    float adh = a_d[d * 8 + l];
    const uint2* hp = (const uint2*)h1;
    uint2 rself = hp[d * 8 + l];
    float asself = __half2float(a_s[d * 8 + l]);
    float ac[8] = {0.f,0.f,0.f,0.f,0.f,0.f,0.f,0.f};
    float denom = 0.f;
    int e = rb + gs;
    int s[4];
#pragma unroll
    for (int q = 0; q < 4; ++q) s[q] = col[e + 4 * q];   // pad-safe preload
    for (; e + 12 < re; ) {
        uint2 rr[4]; float asv[4]; int sn[4];
#pragma unroll
        for (int q = 0; q < 4; ++q) rr[q] = hp[s[q] * 8 + l];
#pragma unroll
        for (int q = 0; q < 4; ++q) asv[q] = __half2float(a_s[s[q] * 8 + l]);
        int en = e + 16;
#pragma unroll
        for (int q = 0; q < 4; ++q) sn[q] = col[en + 4 * q];  // prefetch next
#pragma unroll
        for (int q = 0; q < 4; ++q) {
            float xx = asv[q] + adh;
            xx = xx >= 0.f ? xx : NEG * xx;
            float w = __expf(xx);
            denom += w;
            v2f f0 = __builtin_amdgcn_cvt_pk_f32_fp8((int)rr[q].x, false);
            v2f f1 = __builtin_amdgcn_cvt_pk_f32_fp8((int)rr[q].x, true);
            v2f f2 = __builtin_amdgcn_cvt_pk_f32_fp8((int)rr[q].y, false);
            v2f f3 = __builtin_amdgcn_cvt_pk_f32_fp8((int)rr[q].y, true);
            ac[0] = fmaf(f0.x, w, ac[0]); ac[1] = fmaf(f0.y, w, ac[1]);
            ac[2] = fmaf(f1.x, w, ac[2]); ac[3] = fmaf(f1.y, w, ac[3]);
            ac[4] = fmaf(f2.x, w, ac[4]); ac[5] = fmaf(f2.y, w, ac[5]);
            ac[6] = fmaf(f3.x, w, ac[6]); ac[7] = fmaf(f3.y, w, ac[7]);
        }
        e = en;
#pragma unroll
        for (int q = 0; q < 4; ++q) s[q] = sn[q];
    }
    for (; e < re; e += 4) {
        int s0 = col[e];
        uint2 r0 = hp[s0 * 8 + l];
        float x0 = __half2float(a_s[s0 * 8 + l]) + adh;
        x0 = x0 >= 0.f ? x0 : NEG * x0;
        float w0 = __expf(x0);
        denom += w0;
        v2f f0 = __builtin_amdgcn_cvt_pk_f32_fp8((int)r0.x, false);
        v2f f1 = __builtin_amdgcn_cvt_pk_f32_fp8((int)r0.x, true);
        v2f f2 = __builtin_amdgcn_cvt_pk_f32_fp8((int)r0.y, false);
        v2f f3 = __builtin_amdgcn_cvt_pk_f32_fp8((int)r0.y, true);
        ac[0] = fmaf(f0.x, w0, ac[0]); ac[1] = fmaf(f0.y, w0, ac[1]);
        ac[2] = fmaf(f1.x, w0, ac[2]); ac[3] = fmaf(f1.y, w0, ac[3]);
        ac[4] = fmaf(f2.x, w0, ac[4]); ac[5] = fmaf(f2.y, w0, ac[5]);
        ac[6] = fmaf(f3.x, w0, ac[6]); ac[7] = fmaf(f3.y, w0, ac[7]);
    }
    if (gs == 0) {      // self-loop contribution
        float es = asself + adh;
        es = es >= 0.f ? es : NEG * es;
        float w = __expf(es);
        denom += w;
        v2f f0 = __builtin_amdgcn_cvt_pk_f32_fp8((int)rself.x, false);
        v2f f1 = __builtin_amdgcn_cvt_pk_f32_fp8((int)rself.x, true);
        v2f f2 = __builtin_amdgcn_cvt_pk_f32_fp8((int)rself.y, false);
        v2f f3 = __builtin_amdgcn_cvt_pk_f32_fp8((int)rself.y, true);
        ac[0] = fmaf(f0.x, w, ac[0]); ac[1] = fmaf(f0.y, w, ac[1]);
        ac[2] = fmaf(f1.x, w, ac[2]); ac[3] = fmaf(f1.y, w, ac[3]);
        ac[4] = fmaf(f2.x, w, ac[4]); ac[5] = fmaf(f2.y, w, ac[5]);
        ac[6] = fmaf(f3.x, w, ac[6]); ac[7] = fmaf(f3.y, w, ac[7]);
    }
#pragma unroll
    for (int i = 0; i < 8; ++i) {     // reduce 4 slots (stays within 32-half)
        ac[i] += __shfl_xor(ac[i], 8, 64);
        ac[i] += __shfl_xor(ac[i], 16, 64);
    }
    denom += __shfl_xor(denom, 8, 64);
    denom += __shfl_xor(denom, 16, 64);
    if (gs == 0) {
        float inv = 1.0f / denom;
        float4 b0 = ((const float4*)b1)[l * 2];
        float4 b4 = ((const float4*)b1)[l * 2 + 1];
        float4 r0, r1;
        r0.x = fmaf(ac[0], inv, b0.x); r0.x = r0.x > 0.f ? r0.x : expm1f(r0.x);
        r0.y = fmaf(ac[1], inv, b0.y); r0.y = r0.y > 0.f ? r0.y : expm1f(r0.y);
        r0.z = fmaf(ac[2], inv, b0.z); r0.z = r0.z > 0.f ? r0.z : expm1f(r0.z);
        r0.w = fmaf(ac[3], inv, b0.w); r0.w = r0.w > 0.f ? r0.w : expm1f(r0.w);
        r1.x = fmaf(ac[4], inv, b4.x); r1.x = r1.x > 0.f ? r1.x : expm1f(r1.x);
        r1.y = fmaf(ac[5], inv, b4.y); r1.y = r1.y > 0.f ? r1.y : expm1f(r1.y);
        r1.z = fmaf(ac[6], inv, b4.z); r1.z = r1.z > 0.f ? r1.z : expm1f(r1.z);
        r1.w = fmaf(ac[7], inv, b4.w); r1.w = r1.w > 0.f ? r1.w : expm1f(r1.w);
        ((float4*)out)[d * 16 + l * 2]     = r0;
        ((float4*)out)[d * 16 + l * 2 + 1] = r1;
    }
}

// ===========================================================================
// K5: h2 = hin @ W2, stored fp8 e4m3; a_s2/a_d2 fp32 via 16-lane shfl reduce.
// ===========================================================================
__global__ __launch_bounds__(256)
void k_lin2(const float* __restrict__ hin, const float* __restrict__ W2,
            const float* __restrict__ att_s, const float* __restrict__ att_d,
            unsigned int* __restrict__ h2, float* __restrict__ a_s,
            float* __restrict__ a_d) {
    __shared__ float4 sW4[D1 * 16];      // 16 KB
    __shared__ float sx[16][D1 + 4];
    __shared__ float satt[2 * OUTC];
    int tid = threadIdx.x;
    const float4* W4 = (const float4*)W2;
    for (int i = tid; i < D1 * 16; i += 256) sW4[i] = W4[i];
    if (tid < 128) satt[tid] = (tid < 64) ? att_s[tid] : att_d[tid - 64];
    int node0 = blockIdx.x * 16;
    for (int i = tid; i < 16 * 16; i += 256) {
        int r = i >> 4, kk = i & 15;
        float4 v = ((const float4*)hin)[(node0 + r) * 16 + kk];
        sx[r][kk * 4 + 0] = v.x; sx[r][kk * 4 + 1] = v.y;
        sx[r][kk * 4 + 2] = v.z; sx[r][kk * 4 + 3] = v.w;
    }
    __syncthreads();
    int r = tid >> 4, cg = tid & 15;
    float4 acc = {0.f, 0.f, 0.f, 0.f};
#pragma unroll 8
    for (int k = 0; k < D1; ++k) {
        float xv = sx[r][k];
        float4 wv = sW4[k * 16 + cg];
        acc.x = fmaf(xv, wv.x, acc.x);
        acc.y = fmaf(xv, wv.y, acc.y);
        acc.z = fmaf(xv, wv.z, acc.z);
        acc.w = fmaf(xv, wv.w, acc.w);
    }
    int n = node0 + r;
    int p = __builtin_amdgcn_cvt_pk_fp8_f32(acc.x, acc.y, 0, false);
    p = __builtin_amdgcn_cvt_pk_fp8_f32(acc.z, acc.w, p, true);
    h2[n * 16 + cg] = (unsigned int)p;
    float vs = acc.x * satt[cg * 4] + acc.y * satt[cg * 4 + 1]
             + acc.z * satt[cg * 4 + 2] + acc.w * satt[cg * 4 + 3];
    float vd = acc.x * satt[64 + cg * 4] + acc.y * satt[64 + cg * 4 + 1]
             + acc.z * satt[64 + cg * 4 + 2] + acc.w * satt[64 + cg * 4 + 3];
    for (int off = 1; off < 16; off <<= 1) {
        vs += __shfl_xor(vs, off, 64);
        vd += __shfl_xor(vd, off, 64);
    }
    if (cg == 0) { a_s[n] = vs; a_d[n] = vd; }
}

// ===========================================================================
// Agg layer 2 (1 head). Same 2-node/wave pipelined structure; fused bias +
// mean-pool (LDS staged over 8 nodes/block; batch sorted).
// ===========================================================================
__global__ __launch_bounds__(256, 8)
void k_gat_agg2(const int* __restrict__ rbeg, const int* __restrict__ rend,
                const int* __restrict__ col,
                const float* __restrict__ a_s, const float* __restrict__ a_d,
                const unsigned int* __restrict__ h2, const float* __restrict__ b2,
                const int* __restrict__ batch,
                float* __restrict__ pool, float* __restrict__ cnt) {
    __shared__ float sv[8][64];
    __shared__ int sgi[8];
    int wv = threadIdx.x >> 6;
    int lane = threadIdx.x & 63;
    int half = lane >> 5;
    int idx = wv * 2 + half;
    int d = blockIdx.x * 8 + idx;
    int gs = (lane >> 3) & 3;
    int l = lane & 7;
    int rb = rbeg[d], re = rend[d];
    float ad = a_d[d];
    const uint2* hp = (const uint2*)h2;
    uint2 rself = hp[d * 8 + l];
    float asself = a_s[d];
    if (gs == 0 && l == 0) sgi[idx] = batch[d];
    float ac[8] = {0.f,0.f,0.f,0.f,0.f,0.f,0.f,0.f};
    float denom = 0.f;
    int e = rb + gs;
    int s[4];
#pragma unroll
    for (int q = 0; q < 4; ++q) s[q] = col[e + 4 * q];
    for (; e + 12 < re; ) {
        uint2 rr[4]; float asv[4]; int sn[4];
#pragma unroll
        for (int q = 0; q < 4; ++q) rr[q] = hp[s[q] * 8 + l];
#pragma unroll
        for (int q = 0; q < 4; ++q) asv[q] = a_s[s[q]];
        int en = e + 16;
#pragma unroll
        for (int q = 0; q < 4; ++q) sn[q] = col[en + 4 * q];
#pragma unroll
        for (int q = 0; q < 4; ++q) {
            float xx = asv[q] + ad;
            xx = xx >= 0.f ? xx : NEG * xx;
            float w = __expf(xx);
            denom += w;
            v2f f0 = __builtin_amdgcn_cvt_pk_f32_fp8((int)rr[q].x, false);
            v2f f1 = __builtin_amdgcn_cvt_pk_f32_fp8((int)rr[q].x, true);
            v2f f2 = __builtin_amdgcn_cvt_pk_f32_fp8((int)rr[q].y, false);
            v2f f3 = __builtin_amdgcn_cvt_pk_f32_fp8((int)rr[q].y, true);
            ac[0] = fmaf(f0.x, w, ac[0]); ac[1] = fmaf(f0.y, w, ac[1]);
            ac[2] = fmaf(f1.x, w, ac[2]); ac[3] = fmaf(f1.y, w, ac[3]);
            ac[4] = fmaf(f2.x, w, ac[4]); ac[5] = fmaf(f2.y, w, ac[5]);
            ac[6] = fmaf(f3.x, w, ac[6]); ac[7] = fmaf(f3.y, w, ac[7]);
        }
        e = en;
#pragma unroll
        for (int q = 0; q < 4; ++q) s[q] = sn[q];
    }
    for (; e < re; e += 4) {
        int s0 = col[e];
        uint2 r0 = hp[s0 * 8 + l];
        float x0 = a_s[s0] + ad;
        x0 = x0 >= 0.f ? x0 : NEG * x0;
        float w0 = __expf(x0);
        denom += w0;
        v2f f0 = __builtin_amdgcn_cvt_pk_f32_fp8((int)r0.x, false);
        v2f f1 = __builtin_amdgcn_cvt_pk_f32_fp8((int)r0.x, true);
        v2f f2 = __builtin_amdgcn_cvt_pk_f32_fp8((int)r0.y, false);
        v2f f3 = __builtin_amdgcn_cvt_pk_f32_fp8((int)r0.y, true);
        ac[0] = fmaf(f0.x, w0, ac[0]); ac[1] = fmaf(f0.y, w0, ac[1]);
        ac[2] = fmaf(f1.x, w0, ac[2]); ac[3] = fmaf(f1.y, w0, ac[3]);
        ac[4] = fmaf(f2.x, w0, ac[4]); ac[5] = fmaf(f2.y, w0, ac[5]);
        ac[6] = fmaf(f3.x, w0, ac[6]); ac[7] = fmaf(f3.y, w0, ac[7]);
    }
    if (gs == 0) {
        float es = asself + ad;
        es = es >= 0.f ? es : NEG * es;
        float w = __expf(es);
        denom += w;
        v2f f0 = __builtin_amdgcn_cvt_pk_f32_fp8((int)rself.x, false);
        v2f f1 = __builtin_amdgcn_cvt_pk_f32_fp8((int)rself.x, true);
        v2f f2 = __builtin_amdgcn_cvt_pk_f32_fp8((int)rself.y, false);
        v2f f3 = __builtin_amdgcn_cvt_pk_f32_fp8((int)rself.y, true);
        ac[0] = fmaf(f0.x, w, ac[0]); ac[1] = fmaf(f0.y, w, ac[1]);
        ac[2] = fmaf(f1.x, w, ac[2]); ac[3] = fmaf(f1.y, w, ac[3]);
        ac[4] = fmaf(f2.x, w, ac[4]); ac[5] = fmaf(f2.y, w, ac[5]);
        ac[6] = fmaf(f3.x, w, ac[6]); ac[7] = fmaf(f3.y, w, ac[7]);
    }
#pragma unroll
    for (int i = 0; i < 8; ++i) {
        ac[i] += __shfl_xor(ac[i], 8, 64);
        ac[i] += __shfl_xor(ac[i], 16, 64);
    }
    denom += __shfl_xor(denom, 8, 64);
    denom += __shfl_xor(denom, 16, 64);
    if (gs == 0) {
        float inv = 1.0f / denom;
#pragma unroll
        for (int i = 0; i < 8; ++i)
            sv[idx][l * 8 + i] = fmaf(ac[i], inv, b2[l * 8 + i]);
    }
    __syncthreads();
    int tid = threadIdx.x;
    if (tid < 64) {
        float acc = sv[0][tid]; int curg = sgi[0];
        for (int r = 1; r < 8; ++r) {
            if (sgi[r] == curg) acc += sv[r][tid];
            else { atomicAdd(&pool[curg * 64 + tid], acc); curg = sgi[r]; acc = sv[r][tid]; }
        }
        atomicAdd(&pool[curg * 64 + tid], acc);
    } else if (tid == 64) {
        float c = 1.f; int curg = sgi[0];
        for (int r = 1; r < 8; ++r) {
            if (sgi[r] == curg) c += 1.f;
            else { atomicAdd(&cnt[curg], c); curg = sgi[r]; c = 1.f; }
        }
        atomicAdd(&cnt[curg], c);
    }
}

// K9: g = pool/cnt ; hidden = elu(g@lw1+lb1) ; out = hidden@lw2 + lb2
__global__ __launch_bounds__(128)
void k_mlp(const float* __restrict__ pool, const float* __restrict__ cnt,
           const float* __restrict__ lw1, const float* __restrict__ lb1,
           const float* __restrict__ lw2, const float* __restrict__ lb2,
           float* __restrict__ out) {
    __shared__ float sg[OUTC];
    __shared__ float sh[HID];
    int g = blockIdx.x, tid = threadIdx.x;
    float c = fmaxf(cnt[g], 1.0f);
    if (tid < OUTC) sg[tid] = pool[g * OUTC + tid] / c;
    __syncthreads();
    float acc = lb1[tid];
#pragma unroll 8
    for (int k = 0; k < OUTC; ++k)
        acc = fmaf(sg[k], lw1[k * HID + tid], acc);
    acc = acc > 0.f ? acc : expm1f(acc);
    sh[tid] = acc * lw2[tid];
    __syncthreads();
    for (int off = 64; off >= 1; off >>= 1) {
        if (tid < off) sh[tid] += sh[tid + off];
        __syncthreads();
    }
    if (tid == 0) out[g] = sh[0] + lb2[0];
}

extern "C" void kernel_launch(void* const* d_in, const int* in_sizes, int n_in,
                              void* d_out, int out_size, void* d_ws, size_t ws_size,
                              hipStream_t stream) {
    const float* x    = (const float*)d_in[0];
    const int*   ei   = (const int*)d_in[1];
    const int*   batch= (const int*)d_in[2];
    const float* W1   = (const float*)d_in[3];
    const float* as1  = (const float*)d_in[4];
    const float* ad1  = (const float*)d_in[5];
    const float* b1   = (const float*)d_in[6];
    const float* W2   = (const float*)d_in[7];
    const float* as2  = (const float*)d_in[8];
    const float* ad2  = (const float*)d_in[9];
    const float* b2   = (const float*)d_in[10];
    const float* lw1  = (const float*)d_in[11];
    const float* lb1  = (const float*)d_in[12];
    const float* lw2  = (const float*)d_in[13];
    const float* lb2  = (const float*)d_in[14];
    float* out = (float*)d_out;

    // workspace layout (~67 MB); colv has +1024-int pad for pipelined preloads
    unsigned int* H8 = (unsigned int*)d_ws;          // N*16 uints = fp8 table (6.4 MB)
    float* B    = (float*)(H8 + (size_t)NN * 16);    // N*64 fp32 (25.6 MB)
    float* aD1  = B + (size_t)NN * 64;               // N*8
    float* aS2  = aD1 + NN * 8;                      // N
    float* aD2  = aS2 + NN;                          // N
    float* pool = aD2 + NN;                          // G*64
    float* cnt  = pool + GG * 64;                    // G
    __half* aS1h = (__half*)(cnt + GG);              // N*8 fp16 (1.6 MB)
    int* rbeg   = (int*)(aS1h + (size_t)NN * 8);     // N
    int* rend   = rbeg + NN;                         // N
    int* cursor = rend + NN;                         // BINS
    int* bucket = cursor + BINS;                     // BINS*BCAP (14.4 MB)
    int* colv   = bucket + (size_t)BINS * BCAP;      // BINS*BCAP + pad

    const int* srcv = ei;
    const int* dstv = ei + EE;

    hipMemsetAsync(cursor, 0, BINS * sizeof(int), stream);
    hipMemsetAsync(pool, 0, (size_t)(GG * 64 + GG) * sizeof(float), stream);

    // FUSED: bucket scatter (CSR phase 1) co-scheduled with lin1 GEMM
    k_fused<<<BKBLK + NN / 16, 256, 0, stream>>>(srcv, dstv, cursor, bucket,
                                                 x, W1, as1, ad1, H8, aS1h, aD1);
    k_binCSR<<<BINS, 256, 0, stream>>>(cursor, bucket, colv, rbeg, rend);

    // layer 1 aggregation
    k_gat_agg1<<<NN / 8, 256, 0, stream>>>(rbeg, rend, colv, aS1h, aD1, H8, b1, B);

    // layer 2 (agg fused with bias + mean-pool accumulation)
    k_lin2    <<<NN / 16, 256, 0, stream>>>(B, W2, as2, ad2, H8, aS2, aD2);
    k_gat_agg2<<<NN / 8, 256, 0, stream>>>(rbeg, rend, colv, aS2, aD2, H8, b2, batch, pool, cnt);

    // MLP head
    k_mlp<<<GG, 128, 0, stream>>>(pool, cnt, lw1, lb1, lw2, lb2, out);
}